// Round 2
// baseline (431.105 us; speedup 1.0000x reference)
//
#include <hip/hip_runtime.h>
#include <hip/hip_bf16.h>

// GCN: 2x GCNConv(sym-norm, self-loops) + mean-pool + linear head.
// All float tensors are fp32 (reference dtypes); edge_index is int32.
// Restructured: aggregate-then-transform (L1), transform-then-aggregate (L2)
// so both message-passing phases are 128-wide. CSR-by-dst built per launch
// (inputs restored / ws poisoned before every timed call).

#define FEAT 128   // aggregation width (both layers)

// ---------------- setup kernels ----------------

__global__ void k_init(int* __restrict__ degi, float* __restrict__ pooled, int n) {
    int i = blockIdx.x * blockDim.x + threadIdx.x;
    if (i < n) degi[i] = 1;          // self-loop contributes 1 to in-degree
    if (i < 128) pooled[i] = 0.f;
}

__global__ void k_count(const int* __restrict__ dst, int* __restrict__ degi, int E) {
    int e = blockIdx.x * blockDim.x + threadIdx.x;
    if (e < E) atomicAdd(&degi[dst[e]], 1);
}

__global__ void k_isd(const int* __restrict__ degi, float* __restrict__ isd, int n) {
    int i = blockIdx.x * blockDim.x + threadIdx.x;
    if (i < n) isd[i] = rsqrtf((float)degi[i]);
}

// exclusive scan of (degi[i]-1) = real in-edge counts, chunked by 1024
__global__ void k_scan1(const int* __restrict__ degi, int* __restrict__ off,
                        int* __restrict__ bsum, int n) {
    __shared__ int s[1024];
    int t = threadIdx.x;
    int i = blockIdx.x * 1024 + t;
    int c = (i < n) ? (degi[i] - 1) : 0;
    s[t] = c;
    __syncthreads();
    for (int d = 1; d < 1024; d <<= 1) {
        int v = (t >= d) ? s[t - d] : 0;
        __syncthreads();
        s[t] += v;
        __syncthreads();
    }
    if (i < n) off[i] = s[t] - c;        // exclusive within block
    if (t == 1023) bsum[blockIdx.x] = s[t];
}

__global__ void k_scan2(int* __restrict__ bsum, int nb) {
    if (threadIdx.x == 0 && blockIdx.x == 0) {
        int run = 0;
        for (int b = 0; b < nb; ++b) { int v = bsum[b]; bsum[b] = run; run += v; }
    }
}

__global__ void k_scan3(int* __restrict__ off, int* __restrict__ cur,
                        const int* __restrict__ bsum, int n, int total) {
    int i = blockIdx.x * blockDim.x + threadIdx.x;
    if (i < n) { int v = off[i] + bsum[i >> 10]; off[i] = v; cur[i] = v; }
    if (i == n) off[n] = total;
}

__global__ void k_fill(const int* __restrict__ src, const int* __restrict__ dst,
                       int* __restrict__ cur, int* __restrict__ csr, int E) {
    int e = blockIdx.x * blockDim.x + threadIdx.x;
    if (e < E) {
        int p = atomicAdd(&cur[dst[e]], 1);
        csr[p] = src[e];
    }
}

// ---------------- aggregation: out[n] = isd[n] * sum_{s in N(n)} isd[s]*X[s] + X[n]/deg[n]

__global__ __launch_bounds__(256) void k_agg(const float* __restrict__ X,
                                             const int* __restrict__ off,
                                             const int* __restrict__ csr,
                                             const float* __restrict__ isd,
                                             float* __restrict__ out, int n) {
    int wid  = (blockIdx.x * 256 + threadIdx.x) >> 6;   // one wave per node
    int lane = threadIdx.x & 63;                         // lane -> features 2*lane,2*lane+1
    if (wid >= n) return;
    int beg = off[wid], end = off[wid + 1];
    float a0 = 0.f, a1 = 0.f;
    int e = beg;
    for (; e + 2 <= end; e += 2) {                       // 2-edge unroll for MLP
        int s0 = csr[e], s1 = csr[e + 1];
        float w0 = isd[s0], w1 = isd[s1];
        float2 v0 = ((const float2*)X)[(long)s0 * 64 + lane];
        float2 v1 = ((const float2*)X)[(long)s1 * 64 + lane];
        a0 += w0 * v0.x + w1 * v1.x;
        a1 += w0 * v0.y + w1 * v1.y;
    }
    if (e < end) {
        int s0 = csr[e];
        float w0 = isd[s0];
        float2 v0 = ((const float2*)X)[(long)s0 * 64 + lane];
        a0 += w0 * v0.x;
        a1 += w0 * v0.y;
    }
    float wn = isd[wid];
    float2 xv = ((const float2*)X)[(long)wid * 64 + lane];
    float invdeg = wn * wn;                              // self-loop norm = 1/deg
    float2 r;
    r.x = wn * a0 + xv.x * invdeg;
    r.y = wn * a1 + xv.y * invdeg;
    ((float2*)out)[(long)wid * 64 + lane] = r;
}

// ---------------- fp32 GEMM: C[M,N] = A[M,K] @ B[K,N] (+bias)(+relu)

#define GBM 64
#define GBN 64
#define GBK 32

__global__ __launch_bounds__(256) void k_gemm(const float* __restrict__ A,
                                              const float* __restrict__ B,
                                              const float* __restrict__ bias,
                                              float* __restrict__ C,
                                              int M, int N, int K, int relu) {
    __shared__ float As[GBK][GBM + 4];   // A^T tile
    __shared__ float Bs[GBK][GBN + 4];
    int tid  = threadIdx.x;
    int col0 = blockIdx.x * GBN;
    int row0 = blockIdx.y * GBM;
    int tx = tid & 15, ty = tid >> 4;    // 16x16 threads, 4x4 micro-tile each
    float acc[4][4] = {{0.f}};

    for (int k0 = 0; k0 < K; k0 += GBK) {
        // A tile 64x32: float4 loads, store transposed
        for (int i = tid; i < 512; i += 256) {
            int r = i >> 3;              // 0..63 (row within tile)
            int c = (i & 7) << 2;        // 0..28 (k within tile)
            float4 v = make_float4(0.f, 0.f, 0.f, 0.f);
            int gr = row0 + r;
            if (gr < M) v = *(const float4*)(A + (size_t)gr * K + k0 + c);
            As[c + 0][r] = v.x;
            As[c + 1][r] = v.y;
            As[c + 2][r] = v.z;
            As[c + 3][r] = v.w;
        }
        // B tile 32x64
        for (int i = tid; i < 512; i += 256) {
            int r = i >> 4;              // 0..31
            int c = (i & 15) << 2;       // 0..60
            float4 v = *(const float4*)(B + (size_t)(k0 + r) * N + (col0 + c));
            *(float4*)(&Bs[r][c]) = v;
        }
        __syncthreads();
#pragma unroll
        for (int k = 0; k < GBK; ++k) {
            float4 av = *(const float4*)(&As[k][ty * 4]);
            float4 bv = *(const float4*)(&Bs[k][tx * 4]);
            float a4[4] = {av.x, av.y, av.z, av.w};
            float b4[4] = {bv.x, bv.y, bv.z, bv.w};
#pragma unroll
            for (int i2 = 0; i2 < 4; ++i2)
#pragma unroll
                for (int j = 0; j < 4; ++j) acc[i2][j] += a4[i2] * b4[j];
        }
        __syncthreads();
    }

    float bz[4] = {0.f, 0.f, 0.f, 0.f};
    if (bias) {
#pragma unroll
        for (int j = 0; j < 4; ++j) bz[j] = bias[col0 + tx * 4 + j];
    }
#pragma unroll
    for (int i2 = 0; i2 < 4; ++i2) {
        int gr = row0 + ty * 4 + i2;
        if (gr >= M) continue;
        float4 o;
        o.x = acc[i2][0] + bz[0];
        o.y = acc[i2][1] + bz[1];
        o.z = acc[i2][2] + bz[2];
        o.w = acc[i2][3] + bz[3];
        if (relu) {
            o.x = fmaxf(o.x, 0.f); o.y = fmaxf(o.y, 0.f);
            o.z = fmaxf(o.z, 0.f); o.w = fmaxf(o.w, 0.f);
        }
        *(float4*)(C + (size_t)gr * N + col0 + tx * 4) = o;
    }
}

// ---------------- epilogue: relu(agg2 + b2), column-sum into pooled[128]

__global__ __launch_bounds__(256) void k_post(const float* __restrict__ agg2,
                                              const float* __restrict__ b2,
                                              float* __restrict__ pooled, int n) {
    __shared__ float s[256];
    int f  = threadIdx.x & 127;
    int rg = threadIdx.x >> 7;           // 0/1: two rows in flight per block
    float bias = b2[f];
    float acc = 0.f;
    for (int r = blockIdx.x * 2 + rg; r < n; r += gridDim.x * 2) {
        float v = agg2[(size_t)r * 128 + f] + bias;
        acc += fmaxf(v, 0.f);
    }
    s[threadIdx.x] = acc;
    __syncthreads();
    if (rg == 0) atomicAdd(&pooled[f], s[f] + s[128 + f]);
}

__global__ void k_final(const float* __restrict__ pooled,
                        const float* __restrict__ Wfc,
                        const float* __restrict__ bfc,
                        float* __restrict__ out, float invN) {
    __shared__ float s[128];
    int t = threadIdx.x;
    float v = pooled[t] * invN * Wfc[t];
    s[t] = v;
    __syncthreads();
    for (int d = 64; d > 0; d >>= 1) {
        if (t < d) s[t] += s[t + d];
        __syncthreads();
    }
    if (t == 0) out[0] = s[0] + bfc[0];
}

// ---------------- launch ----------------

extern "C" void kernel_launch(void* const* d_in, const int* in_sizes, int n_in,
                              void* d_out, int out_size, void* d_ws, size_t ws_size,
                              hipStream_t stream) {
    const float* x   = (const float*)d_in[0];
    const int*   ei  = (const int*)d_in[1];
    const float* W1  = (const float*)d_in[2];
    const float* b1  = (const float*)d_in[3];
    const float* W2  = (const float*)d_in[4];
    const float* b2  = (const float*)d_in[5];
    const float* Wfc = (const float*)d_in[6];
    const float* bfc = (const float*)d_in[7];
    float* out = (float*)d_out;

    int N = in_sizes[0] / FEAT;     // 50000
    int E = in_sizes[1] / 2;        // 800000
    const int* src = ei;
    const int* dst = ei + E;

    char* p = (char*)d_ws;
    auto alloc = [&](size_t bytes) {
        char* r = p;
        p += (bytes + 255) & ~(size_t)255;
        return r;
    };
    int*   degi   = (int*)  alloc((size_t)N * 4);
    float* isd    = (float*)alloc((size_t)N * 4);
    int*   off    = (int*)  alloc((size_t)(N + 1) * 4);
    int*   cur    = (int*)  alloc((size_t)N * 4);
    int*   csr    = (int*)  alloc((size_t)E * 4);
    int*   bsum   = (int*)  alloc(64 * 4);
    float* aggbuf = (float*)alloc((size_t)N * 128 * 4);   // agg1, reused for agg2
    float* h1     = (float*)alloc((size_t)N * 256 * 4);
    float* t2     = (float*)alloc((size_t)N * 128 * 4);
    float* pooled = (float*)alloc(128 * 4);

    // degree + normalization + CSR build
    k_init<<<(N + 255) / 256, 256, 0, stream>>>(degi, pooled, N);
    k_count<<<(E + 255) / 256, 256, 0, stream>>>(dst, degi, E);
    k_isd<<<(N + 255) / 256, 256, 0, stream>>>(degi, isd, N);
    int nb = (N + 1023) / 1024;
    k_scan1<<<nb, 1024, 0, stream>>>(degi, off, bsum, N);
    k_scan2<<<1, 64, 0, stream>>>(bsum, nb);
    k_scan3<<<(N + 1 + 255) / 256, 256, 0, stream>>>(off, cur, bsum, N, E);
    k_fill<<<(E + 255) / 256, 256, 0, stream>>>(src, dst, cur, csr, E);

    // layer 1: aggregate(x) -> GEMM(128->256) + b1 + relu
    k_agg<<<(N + 3) / 4, 256, 0, stream>>>(x, off, csr, isd, aggbuf, N);
    dim3 g1(256 / GBN, (N + GBM - 1) / GBM);
    k_gemm<<<g1, 256, 0, stream>>>(aggbuf, W1, b1, h1, N, 256, 128, 1);

    // layer 2: GEMM(256->128) -> aggregate -> (+b2, relu fused into pool)
    dim3 g2(128 / GBN, (N + GBM - 1) / GBM);
    k_gemm<<<g2, 256, 0, stream>>>(h1, W2, nullptr, t2, N, 128, 256, 0);
    k_agg<<<(N + 3) / 4, 256, 0, stream>>>(t2, off, csr, isd, aggbuf, N);

    // mean-pool + head
    k_post<<<512, 256, 0, stream>>>(aggbuf, b2, pooled, N);
    k_final<<<1, 128, 0, stream>>>(pooled, Wfc, bfc, out, 1.0f / (float)N);
}

// Round 3
// 339.186 us; speedup vs baseline: 1.2710x; 1.2710x over previous
//
#include <hip/hip_runtime.h>

// GCN: 2x GCNConv(sym-norm, self-loops) + mean-pool + linear head.
// Round 3: bf16 MFMA GEMMs (W pre-swizzled to fragment order, LDS-staged),
// bf16 feature arrays for both gather phases (halves gather traffic),
// fp32 accumulation everywhere. CSR-by-dst rebuilt per launch.

#define FEAT 128

typedef __attribute__((ext_vector_type(8))) short short8;   // 8 bf16 (4 VGPRs)
typedef __attribute__((ext_vector_type(4))) float float4v;  // 4 fp32 acc

// bf16 helpers (raw ushort storage; round-to-nearest-even)
__device__ __forceinline__ unsigned short f2b(float f) {
    unsigned int u = __float_as_uint(f);
    unsigned int r = (u + 0x7fffu + ((u >> 16) & 1u)) >> 16;
    return (unsigned short)r;
}
__device__ __forceinline__ float b_lo(unsigned int u) { return __uint_as_float(u << 16); }
__device__ __forceinline__ float b_hi(unsigned int u) { return __uint_as_float(u & 0xffff0000u); }

// ---------------- setup kernels ----------------

__global__ void k_init(int* __restrict__ degi, float* __restrict__ pooled, int n) {
    int i = blockIdx.x * blockDim.x + threadIdx.x;
    if (i < n) degi[i] = 1;          // self-loop
    if (i < 128) pooled[i] = 0.f;
}

__global__ void k_count(const int* __restrict__ dst, int* __restrict__ degi, int E) {
    int e = blockIdx.x * blockDim.x + threadIdx.x;
    if (e < E) atomicAdd(&degi[dst[e]], 1);
}

__global__ void k_isd(const int* __restrict__ degi, float* __restrict__ isd, int n) {
    int i = blockIdx.x * blockDim.x + threadIdx.x;
    if (i < n) isd[i] = rsqrtf((float)degi[i]);
}

__global__ void k_scan1(const int* __restrict__ degi, int* __restrict__ off,
                        int* __restrict__ bsum, int n) {
    __shared__ int s[1024];
    int t = threadIdx.x;
    int i = blockIdx.x * 1024 + t;
    int c = (i < n) ? (degi[i] - 1) : 0;
    s[t] = c;
    __syncthreads();
    for (int d = 1; d < 1024; d <<= 1) {
        int v = (t >= d) ? s[t - d] : 0;
        __syncthreads();
        s[t] += v;
        __syncthreads();
    }
    if (i < n) off[i] = s[t] - c;
    if (t == 1023) bsum[blockIdx.x] = s[t];
}

__global__ void k_scan2(int* __restrict__ bsum, int nb) {
    if (threadIdx.x == 0 && blockIdx.x == 0) {
        int run = 0;
        for (int b = 0; b < nb; ++b) { int v = bsum[b]; bsum[b] = run; run += v; }
    }
}

__global__ void k_scan3(int* __restrict__ off, int* __restrict__ cur,
                        const int* __restrict__ bsum, int n, int total) {
    int i = blockIdx.x * blockDim.x + threadIdx.x;
    if (i < n) { int v = off[i] + bsum[i >> 10]; off[i] = v; cur[i] = v; }
    if (i == n) off[n] = total;
}

__global__ void k_fill(const int* __restrict__ src, const int* __restrict__ dst,
                       int* __restrict__ cur, int* __restrict__ csr, int E) {
    int e = blockIdx.x * blockDim.x + threadIdx.x;
    if (e < E) {
        int p = atomicAdd(&cur[dst[e]], 1);
        csr[p] = src[e];
    }
}

// fp32 -> bf16 cast (x), 4 elems/thread
__global__ void k_castx(const float* __restrict__ x, unsigned short* __restrict__ xb, int total4) {
    int i = blockIdx.x * blockDim.x + threadIdx.x;
    if (i < total4) {
        float4 v = ((const float4*)x)[i];
        unsigned int lo = (unsigned int)f2b(v.x) | ((unsigned int)f2b(v.y) << 16);
        unsigned int hi = (unsigned int)f2b(v.z) | ((unsigned int)f2b(v.w) << 16);
        ((uint2*)xb)[i] = make_uint2(lo, hi);
    }
}

// W [K,N] fp32 row-major -> bf16 in MFMA B-fragment order:
// out[((kt*NT + nt)*64 + lane)*8 + j] = W[kt*32 + (lane>>4)*8 + j][nt*16 + (lane&15)]
__global__ void k_wswz(const float* __restrict__ W, unsigned short* __restrict__ out,
                       int K, int N) {
    int tid = blockIdx.x * blockDim.x + threadIdx.x;
    int total = (K >> 5) * (N >> 4) * 64;
    if (tid >= total) return;
    int lane = tid & 63, f = tid >> 6;
    int NT = N >> 4;
    int nt = f % NT, kt = f / NT;
    int m = lane & 15, quad = lane >> 4;
    unsigned short v[8];
#pragma unroll
    for (int j = 0; j < 8; ++j)
        v[j] = f2b(W[(size_t)(kt * 32 + quad * 8 + j) * N + nt * 16 + m]);
    short8 pk;
#pragma unroll
    for (int j = 0; j < 8; ++j) pk[j] = (short)v[j];
    *(short8*)(out + (size_t)tid * 8) = pk;
}

// ---------------- aggregation (bf16 features, fp32 accum) ----------------
// out[n] = isd[n] * sum_{s in N(n)} isd[s]*X[s] + X[n]/deg[n]

template <bool OUTBF>
__global__ __launch_bounds__(256) void k_aggb(const unsigned int* __restrict__ Xb,
                                              const int* __restrict__ off,
                                              const int* __restrict__ csr,
                                              const float* __restrict__ isd,
                                              void* __restrict__ out, int n) {
    int wid  = (blockIdx.x * 256 + threadIdx.x) >> 6;   // one wave per node
    int lane = threadIdx.x & 63;                         // lane -> feats 2*lane, 2*lane+1
    if (wid >= n) return;
    int beg = off[wid], end = off[wid + 1];
    float a0 = 0.f, a1 = 0.f;
    int e = beg;
    for (; e + 4 <= end; e += 4) {                       // 4-edge unroll for MLP
        int s0 = csr[e], s1 = csr[e + 1], s2 = csr[e + 2], s3 = csr[e + 3];
        float w0 = isd[s0], w1 = isd[s1], w2 = isd[s2], w3 = isd[s3];
        unsigned int u0 = Xb[(size_t)s0 * 64 + lane];
        unsigned int u1 = Xb[(size_t)s1 * 64 + lane];
        unsigned int u2 = Xb[(size_t)s2 * 64 + lane];
        unsigned int u3 = Xb[(size_t)s3 * 64 + lane];
        a0 += w0 * b_lo(u0) + w1 * b_lo(u1) + w2 * b_lo(u2) + w3 * b_lo(u3);
        a1 += w0 * b_hi(u0) + w1 * b_hi(u1) + w2 * b_hi(u2) + w3 * b_hi(u3);
    }
    for (; e < end; ++e) {
        int s0 = csr[e];
        float w0 = isd[s0];
        unsigned int u0 = Xb[(size_t)s0 * 64 + lane];
        a0 += w0 * b_lo(u0);
        a1 += w0 * b_hi(u0);
    }
    float wn = isd[wid];
    unsigned int ux = Xb[(size_t)wid * 64 + lane];
    float inv = wn * wn;                                 // self-loop norm = 1/deg
    float r0 = wn * a0 + b_lo(ux) * inv;
    float r1 = wn * a1 + b_hi(ux) * inv;
    if (OUTBF) {
        ((unsigned int*)out)[(size_t)wid * 64 + lane] =
            (unsigned int)f2b(r0) | ((unsigned int)f2b(r1) << 16);
    } else {
        ((float2*)out)[(size_t)wid * 64 + lane] = make_float2(r0, r1);
    }
}

// ---------------- bf16 MFMA GEMM: C[M,N] = A[M,K] @ W[K,N] ----------------
// A bf16 row-major; Wz bf16 pre-swizzled fragment order; C bf16.
// Block = 4 waves x 16 rows = 64 rows, each wave covers all N columns.

template <int K, int N, bool BIASRELU>
__global__ __launch_bounds__(256) void k_gemm_mfma(const unsigned short* __restrict__ A,
                                                   const unsigned short* __restrict__ Wz,
                                                   const float* __restrict__ bias,
                                                   unsigned short* __restrict__ C, int M) {
    constexpr int NT = N / 16;
    constexpr int KT = K / 32;
    __shared__ short8 wsh[KT * NT * 64];                 // = K*N*2 bytes (64 KB)

    int tid = threadIdx.x;
    for (int i = tid; i < KT * NT * 64; i += 256) wsh[i] = ((const short8*)Wz)[i];
    __syncthreads();

    int lane = tid & 63;
    int wm   = tid >> 6;                                 // wave id 0..3
    int m    = lane & 15, quad = lane >> 4;

    long arow = (long)blockIdx.x * 64 + wm * 16 + m;     // A-frag row (m = lane&15)
    if (arow >= M) arow = M - 1;                         // clamp; stores guarded below
    const short8* Ap = (const short8*)(A + (size_t)arow * K);

    float4v acc[NT];
    float4v zero = {0.f, 0.f, 0.f, 0.f};
#pragma unroll
    for (int nt = 0; nt < NT; ++nt) acc[nt] = zero;

    for (int kt = 0; kt < KT; ++kt) {
        short8 a = Ap[kt * 4 + quad];                    // 8 contiguous bf16 in k
        const short8* wp = wsh + (size_t)kt * NT * 64 + lane;
#pragma unroll
        for (int nt = 0; nt < NT; ++nt)
            acc[nt] = __builtin_amdgcn_mfma_f32_16x16x32_bf16(a, wp[nt * 64], acc[nt], 0, 0, 0);
    }

    // C/D layout: col = lane&15, row = quad*4 + reg
    int orow0 = blockIdx.x * 64 + wm * 16 + quad * 4;
#pragma unroll
    for (int nt = 0; nt < NT; ++nt) {
        int col = nt * 16 + m;
        float bz = BIASRELU ? bias[col] : 0.f;
#pragma unroll
        for (int reg = 0; reg < 4; ++reg) {
            int orow = orow0 + reg;
            if (orow < M) {
                float v = acc[nt][reg] + bz;
                if (BIASRELU) v = fmaxf(v, 0.f);
                C[(size_t)orow * N + col] = f2b(v);
            }
        }
    }
}

// ---------------- epilogue: relu(agg2 + b2), column-sum into pooled[128]

__global__ __launch_bounds__(256) void k_post(const float* __restrict__ agg2,
                                              const float* __restrict__ b2,
                                              float* __restrict__ pooled, int n) {
    __shared__ float s[256];
    int f  = threadIdx.x & 127;
    int rg = threadIdx.x >> 7;
    float bias = b2[f];
    float acc = 0.f;
    for (int r = blockIdx.x * 2 + rg; r < n; r += gridDim.x * 2) {
        float v = agg2[(size_t)r * 128 + f] + bias;
        acc += fmaxf(v, 0.f);
    }
    s[threadIdx.x] = acc;
    __syncthreads();
    if (rg == 0) atomicAdd(&pooled[f], s[f] + s[128 + f]);
}

__global__ void k_final(const float* __restrict__ pooled,
                        const float* __restrict__ Wfc,
                        const float* __restrict__ bfc,
                        float* __restrict__ out, float invN) {
    __shared__ float s[128];
    int t = threadIdx.x;
    float v = pooled[t] * invN * Wfc[t];
    s[t] = v;
    __syncthreads();
    for (int d = 64; d > 0; d >>= 1) {
        if (t < d) s[t] += s[t + d];
        __syncthreads();
    }
    if (t == 0) out[0] = s[0] + bfc[0];
}

// ---------------- launch ----------------

extern "C" void kernel_launch(void* const* d_in, const int* in_sizes, int n_in,
                              void* d_out, int out_size, void* d_ws, size_t ws_size,
                              hipStream_t stream) {
    const float* x   = (const float*)d_in[0];
    const int*   ei  = (const int*)d_in[1];
    const float* W1  = (const float*)d_in[2];
    const float* b1  = (const float*)d_in[3];
    const float* W2  = (const float*)d_in[4];
    const float* b2  = (const float*)d_in[5];
    const float* Wfc = (const float*)d_in[6];
    const float* bfc = (const float*)d_in[7];
    float* out = (float*)d_out;

    int N = in_sizes[0] / FEAT;     // 50000
    int E = in_sizes[1] / 2;        // 800000
    const int* src = ei;
    const int* dst = ei + E;

    char* p = (char*)d_ws;
    auto alloc = [&](size_t bytes) {
        char* r = p;
        p += (bytes + 255) & ~(size_t)255;
        return r;
    };
    int*   degi = (int*)  alloc((size_t)N * 4);
    float* isd  = (float*)alloc((size_t)N * 4);
    int*   off  = (int*)  alloc((size_t)(N + 1) * 4);
    int*   cur  = (int*)  alloc((size_t)N * 4);
    int*   csr  = (int*)  alloc((size_t)E * 4);
    int*   bsum = (int*)  alloc(64 * 4);
    unsigned short* xb   = (unsigned short*)alloc((size_t)N * 128 * 2);  // x as bf16
    unsigned short* aggb = (unsigned short*)alloc((size_t)N * 128 * 2);  // agg1 out bf16
    unsigned short* h1b  = (unsigned short*)alloc((size_t)N * 256 * 2);  // relu(agg1@W1+b1)
    unsigned short* t2b  = (unsigned short*)alloc((size_t)N * 128 * 2);  // h1@W2
    float* aggbuf        = (float*)alloc((size_t)N * 128 * 4);           // agg2 out fp32
    unsigned short* w1z  = (unsigned short*)alloc(128 * 256 * 2);
    unsigned short* w2z  = (unsigned short*)alloc(256 * 128 * 2);
    float* pooled        = (float*)alloc(128 * 4);

    // degree + normalization + CSR build
    k_init<<<(N + 255) / 256, 256, 0, stream>>>(degi, pooled, N);
    k_count<<<(E + 255) / 256, 256, 0, stream>>>(dst, degi, E);
    k_isd<<<(N + 255) / 256, 256, 0, stream>>>(degi, isd, N);
    int nb = (N + 1023) / 1024;
    k_scan1<<<nb, 1024, 0, stream>>>(degi, off, bsum, N);
    k_scan2<<<1, 64, 0, stream>>>(bsum, nb);
    k_scan3<<<(N + 1 + 255) / 256, 256, 0, stream>>>(off, cur, bsum, N, E);
    k_fill<<<(E + 255) / 256, 256, 0, stream>>>(src, dst, cur, csr, E);

    // casts + weight swizzles
    int total4 = N * 128 / 4;
    k_castx<<<(total4 + 255) / 256, 256, 0, stream>>>(x, xb, total4);
    k_wswz<<<(4 * 16 * 64 + 255) / 256, 256, 0, stream>>>(W1, w1z, 128, 256);
    k_wswz<<<(8 * 8 * 64 + 255) / 256, 256, 0, stream>>>(W2, w2z, 256, 128);

    int gblk = (N + 63) / 64;

    // layer 1: aggregate(xb) -> MFMA GEMM(128->256) + b1 + relu -> h1b
    k_aggb<true><<<(N + 3) / 4, 256, 0, stream>>>((const unsigned int*)xb, off, csr, isd, aggb, N);
    k_gemm_mfma<128, 256, true><<<gblk, 256, 0, stream>>>(aggb, w1z, b1, h1b, N);

    // layer 2: MFMA GEMM(256->128) -> aggregate -> (+b2, relu fused into pool)
    k_gemm_mfma<256, 128, false><<<gblk, 256, 0, stream>>>(h1b, w2z, nullptr, t2b, N);
    k_aggb<false><<<(N + 3) / 4, 256, 0, stream>>>((const unsigned int*)t2b, off, csr, isd, aggbuf, N);

    // mean-pool + head
    k_post<<<512, 256, 0, stream>>>(aggbuf, b2, pooled, N);
    k_final<<<1, 128, 0, stream>>>(pooled, Wfc, bfc, out, 1.0f / (float)N);
}

// Round 4
// 303.487 us; speedup vs baseline: 1.4205x; 1.1176x over previous
//
#include <hip/hip_runtime.h>

// GCN: 2x GCNConv(sym-norm, self-loops) + mean-pool + linear head.
// Round 4: bucketed CSR build (LDS atomics only, single-writer csr regions,
// kills the 52MB write-amplification of atomic k_fill + global-atomic k_count),
// isd pre-scaled features (no isd gather in agg loops), ushort csr,
// LDS-free MFMA GEMMs (W read from L1/L2), bf16 agg2 output.

#define FEAT 128
#define TILE 16384   // edges per bucketing workgroup

typedef __attribute__((ext_vector_type(8))) short short8;   // 8 bf16
typedef __attribute__((ext_vector_type(4))) float float4v;  // 4 fp32 acc

__device__ __forceinline__ unsigned int f2b(float f) {      // rne bf16 (as uint)
    unsigned int u = __float_as_uint(f);
    return (u + 0x7fffu + ((u >> 16) & 1u)) >> 16;
}
__device__ __forceinline__ float b_lo(unsigned int u) { return __uint_as_float(u << 16); }
__device__ __forceinline__ float b_hi(unsigned int u) { return __uint_as_float(u & 0xffff0000u); }

// ---------------- bucketed CSR build ----------------
// bucket(d) = d >> 10 (1024 nodes per bucket), B = ceil(N/1024) <= 64.

__global__ __launch_bounds__(1024) void k_p1(const int* __restrict__ dst,
                                             int* __restrict__ cnt, int E, int B, int NW) {
    __shared__ int h[64];
    int t = threadIdx.x, w = blockIdx.x;
    if (t < B) h[t] = 0;
    __syncthreads();
    int e0 = w * TILE, e1 = min(e0 + TILE, E);
    for (int e = e0 + t; e < e1; e += 1024) atomicAdd(&h[dst[e] >> 10], 1);
    __syncthreads();
    if (t < B) cnt[t * NW + w] = h[t];      // bucket-major
}

// exclusive scan of cnt[0..L) in place; single WG; L <= 3072
__global__ __launch_bounds__(1024) void k_bscan(int* __restrict__ cnt, int L) {
    __shared__ int s[1024];
    int t = threadIdx.x;
    int v[3]; int sum = 0;
#pragma unroll
    for (int j = 0; j < 3; ++j) {
        int idx = t * 3 + j;
        int x = (idx < L) ? cnt[idx] : 0;
        v[j] = sum; sum += x;
    }
    s[t] = sum;
    __syncthreads();
    for (int d = 1; d < 1024; d <<= 1) {
        int x = (t >= d) ? s[t - d] : 0;
        __syncthreads();
        s[t] += x;
        __syncthreads();
    }
    int pre = (t > 0) ? s[t - 1] : 0;
#pragma unroll
    for (int j = 0; j < 3; ++j) {
        int idx = t * 3 + j;
        if (idx < L) cnt[idx] = pre + v[j];
    }
}

__global__ __launch_bounds__(1024) void k_p3(const int* __restrict__ src,
                                             const int* __restrict__ dst,
                                             const int* __restrict__ cnt,
                                             unsigned int* __restrict__ ebuf,
                                             int E, int B, int NW) {
    __shared__ int cur[64];
    int t = threadIdx.x, w = blockIdx.x;
    if (t < B) cur[t] = cnt[t * NW + w];
    __syncthreads();
    int e0 = w * TILE, e1 = min(e0 + TILE, E);
    for (int e = e0 + t; e < e1; e += 1024) {
        int d = dst[e], s = src[e];
        int p = atomicAdd(&cur[d >> 10], 1);
        ebuf[p] = ((unsigned int)d << 16) | (unsigned int)s;
    }
}

__global__ __launch_bounds__(1024) void k_p4a(const unsigned int* __restrict__ ebuf,
                                              const int* __restrict__ cnt,
                                              int* __restrict__ degi,
                                              int E, int B, int NW, int N) {
    __shared__ int h[1024];
    int t = threadIdx.x, b = blockIdx.x;
    h[t] = 0;
    __syncthreads();
    int s0 = cnt[b * NW];
    int s1 = (b + 1 < B) ? cnt[(b + 1) * NW] : E;
    for (int e = s0 + t; e < s1; e += 1024)
        atomicAdd(&h[(ebuf[e] >> 16) & 1023], 1);
    __syncthreads();
    int node = (b << 10) + t;
    if (node < N) degi[node] = h[t] + 1;     // +1 self-loop
}

__global__ __launch_bounds__(1024) void k_p4b(const unsigned int* __restrict__ ebuf,
                                              const int* __restrict__ cnt,
                                              const int* __restrict__ off,
                                              unsigned short* __restrict__ csr,
                                              int E, int B, int NW, int N) {
    __shared__ int cur[1024];
    int t = threadIdx.x, b = blockIdx.x;
    int node = (b << 10) + t;
    cur[t] = (node < N) ? off[node] : 0;
    __syncthreads();
    int s0 = cnt[b * NW];
    int s1 = (b + 1 < B) ? cnt[(b + 1) * NW] : E;
    for (int e = s0 + t; e < s1; e += 1024) {
        unsigned int v = ebuf[e];
        int p = atomicAdd(&cur[(v >> 16) & 1023], 1);
        csr[p] = (unsigned short)(v & 0xffffu);
    }
}

// ---------------- node scans / misc ----------------

__global__ void k_isd(const int* __restrict__ degi, float* __restrict__ isd, int n) {
    int i = blockIdx.x * blockDim.x + threadIdx.x;
    if (i < n) isd[i] = rsqrtf((float)degi[i]);
}

__global__ void k_scan1(const int* __restrict__ degi, int* __restrict__ off,
                        int* __restrict__ bsum, int n) {
    __shared__ int s[1024];
    int t = threadIdx.x;
    int i = blockIdx.x * 1024 + t;
    int c = (i < n) ? (degi[i] - 1) : 0;
    s[t] = c;
    __syncthreads();
    for (int d = 1; d < 1024; d <<= 1) {
        int v = (t >= d) ? s[t - d] : 0;
        __syncthreads();
        s[t] += v;
        __syncthreads();
    }
    if (i < n) off[i] = s[t] - c;
    if (t == 1023) bsum[blockIdx.x] = s[t];
}

__global__ void k_scan2(int* __restrict__ bsum, int nb) {
    if (threadIdx.x == 0 && blockIdx.x == 0) {
        int run = 0;
        for (int b = 0; b < nb; ++b) { int v = bsum[b]; bsum[b] = run; run += v; }
    }
}

__global__ void k_scan3(int* __restrict__ off, const int* __restrict__ bsum,
                        int n, int total) {
    int i = blockIdx.x * blockDim.x + threadIdx.x;
    if (i < n) off[i] += bsum[i >> 10];
    if (i == n) off[n] = total;
}

__global__ void k_initpool(float* __restrict__ pooled) {
    pooled[threadIdx.x] = 0.f;
}

// xb[n] = bf16(isd[n] * x[n])  (pre-scaled features; 4 floats/thread)
__global__ void k_scalecast(const float* __restrict__ x, const float* __restrict__ isd,
                            uint2* __restrict__ xb, int total4) {
    int i = blockIdx.x * blockDim.x + threadIdx.x;
    if (i >= total4) return;
    float w = isd[i >> 5];
    float4 v = ((const float4*)x)[i];
    unsigned int lo = f2b(v.x * w) | (f2b(v.y * w) << 16);
    unsigned int hi = f2b(v.z * w) | (f2b(v.w * w) << 16);
    xb[i] = make_uint2(lo, hi);
}

// W [K,N] fp32 -> bf16 MFMA B-fragment order
__global__ void k_wswz(const float* __restrict__ W, unsigned short* __restrict__ out,
                       int K, int N) {
    int tid = blockIdx.x * blockDim.x + threadIdx.x;
    int total = (K >> 5) * (N >> 4) * 64;
    if (tid >= total) return;
    int lane = tid & 63, f = tid >> 6;
    int NT = N >> 4;
    int nt = f % NT, kt = f / NT;
    int m = lane & 15, quad = lane >> 4;
    short8 pk;
#pragma unroll
    for (int j = 0; j < 8; ++j)
        pk[j] = (short)f2b(W[(size_t)(kt * 32 + quad * 8 + j) * N + nt * 16 + m]);
    *(short8*)(out + (size_t)tid * 8) = pk;
}

// ---------------- aggregation: out[n] = bf16( isd[n] * (sum_{s in N(n)} Xs[s] + Xs[n]) )
// Xs is pre-scaled by isd[src]. One wave per node; lane holds feature pair.

__global__ __launch_bounds__(256) void k_aggb(const unsigned int* __restrict__ Xb,
                                              const int* __restrict__ off,
                                              const unsigned short* __restrict__ csr,
                                              const float* __restrict__ isd,
                                              unsigned int* __restrict__ out, int n) {
    int wid  = (blockIdx.x * 256 + threadIdx.x) >> 6;
    int lane = threadIdx.x & 63;
    if (wid >= n) return;
    int beg = off[wid], end = off[wid + 1];
    float a0, a1;
    {
        unsigned int ux = Xb[(size_t)wid * 64 + lane];   // self term
        a0 = b_lo(ux); a1 = b_hi(ux);
    }
    int e = beg;
    for (; e + 4 <= end; e += 4) {
        int s0 = csr[e], s1 = csr[e + 1], s2 = csr[e + 2], s3 = csr[e + 3];
        unsigned int u0 = Xb[(size_t)s0 * 64 + lane];
        unsigned int u1 = Xb[(size_t)s1 * 64 + lane];
        unsigned int u2 = Xb[(size_t)s2 * 64 + lane];
        unsigned int u3 = Xb[(size_t)s3 * 64 + lane];
        a0 += b_lo(u0) + b_lo(u1) + b_lo(u2) + b_lo(u3);
        a1 += b_hi(u0) + b_hi(u1) + b_hi(u2) + b_hi(u3);
    }
    for (; e < end; ++e) {
        unsigned int u0 = Xb[(size_t)csr[e] * 64 + lane];
        a0 += b_lo(u0);
        a1 += b_hi(u0);
    }
    float wn = isd[wid];
    out[(size_t)wid * 64 + lane] = f2b(wn * a0) | (f2b(wn * a1) << 16);
}

// ---------------- bf16 MFMA GEMM: C[M,N] = A[M,K] @ W[K,N], W from global (L1/L2-hot)
// MODE 0: plain store; 1: +bias, relu; 2: scale rows by isd (pre-scale for agg2)

template <int K, int N, int MODE>
__global__ __launch_bounds__(256) void k_gemm_mfma(const unsigned short* __restrict__ A,
                                                   const unsigned short* __restrict__ Wz,
                                                   const float* __restrict__ bias,
                                                   const float* __restrict__ isd,
                                                   unsigned short* __restrict__ C, int M) {
    constexpr int NT = N / 16;
    constexpr int KT = K / 32;
    int tid = threadIdx.x;
    int lane = tid & 63;
    int wm   = tid >> 6;
    int m = lane & 15, quad = lane >> 4;

    long arow = (long)blockIdx.x * 64 + wm * 16 + m;
    if (arow >= M) arow = M - 1;                     // clamp; stores guarded
    const short8* Ap = (const short8*)(A + (size_t)arow * K);
    const short8* Wp = (const short8*)Wz + lane;

    float4v acc[NT];
    float4v zero = {0.f, 0.f, 0.f, 0.f};
#pragma unroll
    for (int nt = 0; nt < NT; ++nt) acc[nt] = zero;

#pragma unroll
    for (int kt = 0; kt < KT; ++kt) {
        short8 a = Ap[kt * 4 + quad];
#pragma unroll
        for (int nt = 0; nt < NT; ++nt)
            acc[nt] = __builtin_amdgcn_mfma_f32_16x16x32_bf16(a, Wp[(kt * NT + nt) * 64],
                                                              acc[nt], 0, 0, 0);
    }

    int orow0 = blockIdx.x * 64 + wm * 16 + quad * 4;  // C/D: col=lane&15, row=quad*4+reg
    float sc[4] = {1.f, 1.f, 1.f, 1.f};
    if (MODE == 2) {
#pragma unroll
        for (int reg = 0; reg < 4; ++reg) {
            int r = orow0 + reg;
            sc[reg] = isd[r < M ? r : M - 1];
        }
    }
#pragma unroll
    for (int nt = 0; nt < NT; ++nt) {
        int col = nt * 16 + m;
        float bz = (MODE == 1) ? bias[col] : 0.f;
#pragma unroll
        for (int reg = 0; reg < 4; ++reg) {
            int orow = orow0 + reg;
            if (orow < M) {
                float v = acc[nt][reg];
                if (MODE == 1) v = fmaxf(v + bz, 0.f);
                if (MODE == 2) v = v * sc[reg];
                C[(size_t)orow * N + col] = (unsigned short)f2b(v);
            }
        }
    }
}

// ---------------- pool: pooled[f] += sum_n relu(agg2[n][f] + b2[f])

__global__ __launch_bounds__(256) void k_post(const unsigned int* __restrict__ agg2,
                                              const float* __restrict__ b2,
                                              float* __restrict__ pooled, int n) {
    __shared__ float s0[256], s1[256];
    int f2 = threadIdx.x & 63;       // feature pair
    int rg = threadIdx.x >> 6;       // 0..3 rows in flight
    float bz0 = b2[2 * f2], bz1 = b2[2 * f2 + 1];
    float a0 = 0.f, a1 = 0.f;
    for (int r = blockIdx.x * 4 + rg; r < n; r += gridDim.x * 4) {
        unsigned int u = agg2[(size_t)r * 64 + f2];
        a0 += fmaxf(b_lo(u) + bz0, 0.f);
        a1 += fmaxf(b_hi(u) + bz1, 0.f);
    }
    s0[threadIdx.x] = a0;
    s1[threadIdx.x] = a1;
    __syncthreads();
    if (rg == 0) {
        float t0 = s0[f2] + s0[64 + f2] + s0[128 + f2] + s0[192 + f2];
        float t1 = s1[f2] + s1[64 + f2] + s1[128 + f2] + s1[192 + f2];
        atomicAdd(&pooled[2 * f2], t0);
        atomicAdd(&pooled[2 * f2 + 1], t1);
    }
}

__global__ void k_final(const float* __restrict__ pooled,
                        const float* __restrict__ Wfc,
                        const float* __restrict__ bfc,
                        float* __restrict__ out, float invN) {
    __shared__ float s[128];
    int t = threadIdx.x;
    s[t] = pooled[t] * invN * Wfc[t];
    __syncthreads();
    for (int d = 64; d > 0; d >>= 1) {
        if (t < d) s[t] += s[t + d];
        __syncthreads();
    }
    if (t == 0) out[0] = s[0] + bfc[0];
}

// ---------------- launch ----------------

extern "C" void kernel_launch(void* const* d_in, const int* in_sizes, int n_in,
                              void* d_out, int out_size, void* d_ws, size_t ws_size,
                              hipStream_t stream) {
    const float* x   = (const float*)d_in[0];
    const int*   ei  = (const int*)d_in[1];
    const float* W1  = (const float*)d_in[2];
    const float* b1  = (const float*)d_in[3];
    const float* W2  = (const float*)d_in[4];
    const float* b2  = (const float*)d_in[5];
    const float* Wfc = (const float*)d_in[6];
    const float* bfc = (const float*)d_in[7];
    float* out = (float*)d_out;

    int N = in_sizes[0] / FEAT;     // 50000
    int E = in_sizes[1] / 2;        // 800000
    const int* src = ei;
    const int* dst = ei + E;

    int NW = (E + TILE - 1) / TILE;         // 49
    int B  = (N + 1023) >> 10;              // 49

    char* p = (char*)d_ws;
    auto alloc = [&](size_t bytes) {
        char* r = p;
        p += (bytes + 255) & ~(size_t)255;
        return r;
    };
    int*   cnt  = (int*)  alloc((size_t)B * NW * 4);
    unsigned int*   ebuf = (unsigned int*)  alloc((size_t)E * 4);
    unsigned short* csr  = (unsigned short*)alloc((size_t)E * 2);
    int*   degi = (int*)  alloc((size_t)N * 4);
    float* isd  = (float*)alloc((size_t)N * 4);
    int*   off  = (int*)  alloc((size_t)(N + 1) * 4);
    int*   bsum = (int*)  alloc(64 * 4);
    uint2* xb   = (uint2*)alloc((size_t)N * 32 * 8);                      // bf16 x pre-scaled
    unsigned int* aggb  = (unsigned int*)alloc((size_t)N * 64 * 4);       // agg1 (bf16)
    unsigned short* h1b = (unsigned short*)alloc((size_t)N * 256 * 2);    // relu(agg1@W1+b1)
    unsigned int* t2b   = (unsigned int*)alloc((size_t)N * 64 * 4);       // isd*(h1@W2) (bf16)
    unsigned int* ag2b  = (unsigned int*)alloc((size_t)N * 64 * 4);       // agg2 (bf16)
    unsigned short* w1z = (unsigned short*)alloc(128 * 256 * 2);
    unsigned short* w2z = (unsigned short*)alloc(256 * 128 * 2);
    float* pooled       = (float*)alloc(128 * 4);

    // --- CSR build (bucketed, LDS atomics only) ---
    k_p1<<<NW, 1024, 0, stream>>>(dst, cnt, E, B, NW);
    k_bscan<<<1, 1024, 0, stream>>>(cnt, B * NW);
    k_p3<<<NW, 1024, 0, stream>>>(src, dst, cnt, ebuf, E, B, NW);
    k_p4a<<<B, 1024, 0, stream>>>(ebuf, cnt, degi, E, B, NW, N);
    k_isd<<<(N + 255) / 256, 256, 0, stream>>>(degi, isd, N);
    int nb = (N + 1023) / 1024;
    k_scan1<<<nb, 1024, 0, stream>>>(degi, off, bsum, N);
    k_scan2<<<1, 64, 0, stream>>>(bsum, nb);
    k_scan3<<<(N + 1 + 255) / 256, 256, 0, stream>>>(off, bsum, N, E);
    k_p4b<<<B, 1024, 0, stream>>>(ebuf, cnt, off, csr, E, B, NW, N);

    // --- casts / weights ---
    int total4 = N * FEAT / 4;
    k_scalecast<<<(total4 + 255) / 256, 256, 0, stream>>>(x, isd, xb, total4);
    k_wswz<<<(4 * 16 * 64 + 255) / 256, 256, 0, stream>>>(W1, w1z, 128, 256);
    k_wswz<<<(8 * 8 * 64 + 255) / 256, 256, 0, stream>>>(W2, w2z, 256, 128);
    k_initpool<<<1, 128, 0, stream>>>(pooled);

    int gblk = (N + 63) / 64;

    // layer 1: aggregate -> GEMM(128->256)+b1+relu
    k_aggb<<<(N + 3) / 4, 256, 0, stream>>>((const unsigned int*)xb, off, csr, isd, aggb, N);
    k_gemm_mfma<128, 256, 1><<<gblk, 256, 0, stream>>>((const unsigned short*)aggb, w1z, b1,
                                                       nullptr, h1b, N);
    // layer 2: GEMM(256->128) w/ isd pre-scale -> aggregate
    k_gemm_mfma<256, 128, 2><<<gblk, 256, 0, stream>>>(h1b, w2z, nullptr, isd,
                                                       (unsigned short*)t2b, N);
    k_aggb<<<(N + 3) / 4, 256, 0, stream>>>(t2b, off, csr, isd, ag2b, N);

    // pool + head
    k_post<<<512, 256, 0, stream>>>(ag2b, b2, pooled, N);
    k_final<<<1, 128, 0, stream>>>(pooled, Wfc, bfc, out, 1.0f / (float)N);
}